// Round 3
// baseline (1546.495 us; speedup 1.0000x reference)
//
#include <hip/hip_runtime.h>
#include <stdint.h>

#define NB     8
#define CIN    64
#define COUT   128
#define KCH    5
#define NNODE  49152
#define NEDGE  393216
#define ROWF   (NB*CIN)      // 512 floats per T row (all batches)
#define HN     (NNODE/COUT)  // 384
#define EPS    1e-5f
#define CNTF   393216.0f     // elements per BN group = B*N

#define GN     16            // nodes per gemm block
#define RSTR   516           // LDS row stride (floats): 516%32=4 -> reads 2-way (free)

// ---------------- setup kernels ----------------

__global__ void k_deg(const int* __restrict__ ei, const float* __restrict__ ew,
                      float* __restrict__ deg) {
    int e = blockIdx.x * 256 + threadIdx.x;
    int s = ei[e], d = ei[NEDGE + e];
    if (s != d) atomicAdd(&deg[s], ew[e]);
}

__global__ void k_dinv(const float* __restrict__ deg, float* __restrict__ dinv) {
    int i = blockIdx.x * 256 + threadIdx.x;
    float d = deg[i];
    dinv[i] = d > 0.0f ? rsqrtf(d) : 0.0f;
}

__global__ void k_count(const int* __restrict__ ei, int* __restrict__ cnt) {
    int e = blockIdx.x * 256 + threadIdx.x;
    atomicAdd(&cnt[ei[NEDGE + e]], 1);
}

__global__ void k_scan(const int* __restrict__ cnt, int* __restrict__ rowptr) {
    __shared__ int part[1024];
    int t = threadIdx.x;
    int base = t * 48;                 // 1024*48 = 49152
    int s = 0;
    for (int i = 0; i < 48; ++i) s += cnt[base + i];
    part[t] = s;
    __syncthreads();
    for (int off = 1; off < 1024; off <<= 1) {
        int v = (t >= off) ? part[t - off] : 0;
        __syncthreads();
        part[t] += v;
        __syncthreads();
    }
    int excl = part[t] - s;            // exclusive prefix of this chunk
    for (int i = 0; i < 48; ++i) { rowptr[base + i] = excl; excl += cnt[base + i]; }
    if (t == 1023) rowptr[NNODE] = excl;
}

__global__ void k_scatter(const int* __restrict__ ei, const float* __restrict__ ew,
                          const float* __restrict__ dinv, const int* __restrict__ rowptr,
                          int* __restrict__ cur, int2* __restrict__ ev) {
    int e = blockIdx.x * 256 + threadIdx.x;
    int s = ei[e], d = ei[NEDGE + e];
    float w = (s == d) ? 0.0f : ew[e];
    float v = -dinv[s] * w * dinv[d];
    int pos = rowptr[d] + atomicAdd(&cur[d], 1);
    int2 p; p.x = s; p.y = __float_as_int(v);
    ev[pos] = p;
}

// x (B,CIN,N) == (512, N) row-major  ->  T0 (N, 512)
__global__ void k_transpose(const float* __restrict__ x, float* __restrict__ T) {
    __shared__ float tile[32][33];
    int n0 = blockIdx.x * 32;          // N/32 = 1536
    int r0 = blockIdx.y * 32;          // 512/32 = 16
    int tx = threadIdx.x, ty = threadIdx.y;  // (32,8)
    #pragma unroll
    for (int rr = 0; rr < 4; ++rr)
        tile[ty + rr * 8][tx] = x[(size_t)(r0 + ty + rr * 8) * NNODE + n0 + tx];
    __syncthreads();
    #pragma unroll
    for (int rr = 0; rr < 4; ++rr)
        T[(size_t)(n0 + ty + rr * 8) * ROWF + r0 + tx] = tile[tx][ty + rr * 8];
}

// ---------------- propagation: Tout[n] = alpha * sum_e val*Tprev[col] + beta * Tpp[n]
__global__ __launch_bounds__(256)
void k_prop(const float* __restrict__ Tprev, const float* __restrict__ Tpp,
            float* __restrict__ Tout, const int* __restrict__ rowptr,
            const int2* __restrict__ ev, float alpha, float beta) {
    int n    = (blockIdx.x << 2) | (threadIdx.x >> 6);   // wave per node
    int lane = threadIdx.x & 63;
    int e0 = rowptr[n], e1 = rowptr[n + 1];
    float4 a0 = make_float4(0, 0, 0, 0), a1 = make_float4(0, 0, 0, 0);
    int e = e0;
    if ((e & 1) && e < e1) {              // peel to 16B-align pair loads
        int2 pa = ev[e];
        const float4* qa = (const float4*)(Tprev + (size_t)pa.x * ROWF);
        float4 x0 = qa[lane], x1 = qa[64 + lane];
        float va = __int_as_float(pa.y);
        a0.x += va * x0.x; a0.y += va * x0.y; a0.z += va * x0.z; a0.w += va * x0.w;
        a1.x += va * x1.x; a1.y += va * x1.y; a1.z += va * x1.z; a1.w += va * x1.w;
        ++e;
    }
    for (; e + 1 < e1; e += 2) {          // one int4 = two edges; 4 b128 gathers in flight
        int4 pp = *(const int4*)(ev + e);
        const float4* qa = (const float4*)(Tprev + (size_t)pp.x * ROWF);
        const float4* qb = (const float4*)(Tprev + (size_t)pp.z * ROWF);
        float4 x0 = qa[lane], x1 = qa[64 + lane];
        float4 y0 = qb[lane], y1 = qb[64 + lane];
        float va = __int_as_float(pp.y), vb = __int_as_float(pp.w);
        a0.x += va * x0.x; a0.y += va * x0.y; a0.z += va * x0.z; a0.w += va * x0.w;
        a1.x += va * x1.x; a1.y += va * x1.y; a1.z += va * x1.z; a1.w += va * x1.w;
        a0.x += vb * y0.x; a0.y += vb * y0.y; a0.z += vb * y0.z; a0.w += vb * y0.w;
        a1.x += vb * y1.x; a1.y += vb * y1.y; a1.z += vb * y1.z; a1.w += vb * y1.w;
    }
    if (e < e1) {
        int2 pa = ev[e];
        const float4* qa = (const float4*)(Tprev + (size_t)pa.x * ROWF);
        float4 x0 = qa[lane], x1 = qa[64 + lane];
        float va = __int_as_float(pa.y);
        a0.x += va * x0.x; a0.y += va * x0.y; a0.z += va * x0.z; a0.w += va * x0.w;
        a1.x += va * x1.x; a1.y += va * x1.y; a1.z += va * x1.z; a1.w += va * x1.w;
    }
    float4 r0, r1;
    r0.x = alpha * a0.x; r0.y = alpha * a0.y; r0.z = alpha * a0.z; r0.w = alpha * a0.w;
    r1.x = alpha * a1.x; r1.y = alpha * a1.y; r1.z = alpha * a1.z; r1.w = alpha * a1.w;
    if (beta != 0.0f) {
        const float4* q = (const float4*)(Tpp + (size_t)n * ROWF);
        float4 c0 = q[lane], c1 = q[64 + lane];
        r0.x += beta * c0.x; r0.y += beta * c0.y; r0.z += beta * c0.z; r0.w += beta * c0.w;
        r1.x += beta * c1.x; r1.y += beta * c1.y; r1.z += beta * c1.z; r1.w += beta * c1.w;
    }
    float4* o = (float4*)(Tout + (size_t)n * ROWF);
    o[lane] = r0;
    o[64 + lane] = r1;
}

// ---------------- fused multi-k GEMM, writes permuted (BN-scrambled) layout ----------------
// S[b][j][o*384 + h] (+)= sum_k T_k[n=j+128h][b*64+c] * W[k][c][o]  (+ bias)
// LDS c-slot swizzle: slot s holds data for c = s ^ ((s>>2)&3)  (involution, bits>=2 fixed)
//  -> staging writes 16-way -> 4-way bank conflict; reads stay linear; W row index XORed.
__global__ __launch_bounds__(256, 2)
void k_gemm(float* __restrict__ S,
            const float* __restrict__ T0, const float* __restrict__ T1,
            const float* __restrict__ T2, const float* __restrict__ T3,
            const float* __restrict__ T4,
            const float* __restrict__ Wg, const float* __restrict__ bias,
            float* __restrict__ sums, float* __restrict__ sumsq,
            int kFirst, int kCount, int init, int doStats) {
    __shared__ float rows[GN * RSTR];        // 33 KB
    int t  = threadIdx.x;
    int bid = blockIdx.x;                    // 3072 = 128 j * 24 hblk
    int j  = bid & 127;
    int h0 = (bid >> 7) * GN;
    int i  = t & 15;                         // node within block (consecutive h)
    int og = t >> 4;                         // 0..15
    int o0 = og * 8;

    float acc[8][8];
    #pragma unroll
    for (int b = 0; b < 8; ++b)
        #pragma unroll
        for (int q = 0; q < 8; ++q) acc[b][q] = 0.f;

    for (int kk = 0; kk < kCount; ++kk) {
        const float* Tk = (kk == 0) ? T0 : (kk == 1) ? T1 : (kk == 2) ? T2
                          : (kk == 3) ? T3 : T4;
        int k = kFirst + kk;
        if (kk) __syncthreads();
        // stage 16 node rows (16 x 512 floats) into LDS as [i][c'][b], c' swizzled
        #pragma unroll
        for (int r = 0; r < 8; ++r) {
            int f4 = t + r * 256;
            int ni = f4 >> 7;
            int q4 = f4 & 127;
            int n  = j + 128 * (h0 + ni);
            const float4 v = *(const float4*)(Tk + (size_t)n * ROWF + q4 * 4);
            int b  = q4 >> 4;
            int c0 = (q4 & 15) * 4;
            int sw = q4 & 3;
            // component u holds c=c0+u, stored at slot c0+(u^sw)
            rows[ni * RSTR + (c0 + (0 ^ sw)) * 8 + b] = v.x;
            rows[ni * RSTR + (c0 + (1 ^ sw)) * 8 + b] = v.y;
            rows[ni * RSTR + (c0 + (2 ^ sw)) * 8 + b] = v.z;
            rows[ni * RSTR + (c0 + (3 ^ sw)) * 8 + b] = v.w;
        }
        __syncthreads();
        const float* Wk = Wg + k * (CIN * COUT);
        #pragma unroll 4
        for (int c = 0; c < 64; ++c) {       // c = LDS slot; W row = c ^ ((c>>2)&3)
            const float4 ra = *(const float4*)(rows + i * RSTR + c * 8);
            const float4 rb = *(const float4*)(rows + i * RSTR + c * 8 + 4);
            int cw = c ^ ((c >> 2) & 3);
            const float4 wa = *(const float4*)(Wk + cw * 128 + o0);
            const float4 wb = *(const float4*)(Wk + cw * 128 + o0 + 4);
            float rv[8] = {ra.x, ra.y, ra.z, ra.w, rb.x, rb.y, rb.z, rb.w};
            float wv[8] = {wa.x, wa.y, wa.z, wa.w, wb.x, wb.y, wb.z, wb.w};
            #pragma unroll
            for (int b = 0; b < 8; ++b)
                #pragma unroll
                for (int q = 0; q < 8; ++q)
                    acc[b][q] += rv[b] * wv[q];
        }
    }
    float bv[8];
    #pragma unroll
    for (int q = 0; q < 8; ++q) bv[q] = bias[o0 + q];
    float s_loc = 0.f, q_loc = 0.f;
    #pragma unroll
    for (int b = 0; b < 8; ++b) {
        size_t base = ((size_t)(b * COUT + j)) * NNODE + h0 + i;
        #pragma unroll
        for (int q = 0; q < 8; ++q) {
            size_t a = base + (size_t)(o0 + q) * HN;
            float v = acc[b][q] + bv[q];
            if (init) S[a] = v;
            else      S[a] += v;
            s_loc += v;
            q_loc += v * v;
        }
    }
    if (doStats) {                           // whole block is one BN group j
        __syncthreads();
        rows[t] = s_loc; rows[256 + t] = q_loc;
        __syncthreads();
        for (int o = 128; o > 0; o >>= 1) {
            if (t < o) { rows[t] += rows[t + o]; rows[256 + t] += rows[256 + t + o]; }
            __syncthreads();
        }
        if (t == 0) { atomicAdd(&sums[j], rows[0]); atomicAdd(&sumsq[j], rows[256]); }
    }
}

// ---------------- BN over scrambled groups (fallback path only) ----------------
__global__ void k_bnstats(const float* __restrict__ S, float* __restrict__ sums,
                          float* __restrict__ sumsq) {
    int bj = blockIdx.x;                 // 1024 = 8 b * 128 j
    int j  = bj & 127;
    int t  = threadIdx.x;
    const float4* row = (const float4*)(S + (size_t)bj * NNODE);
    float s = 0.f, sq = 0.f;
    for (int idx = t; idx < NNODE / 4; idx += 256) {
        float4 v = row[idx];
        s  += v.x + v.y + v.z + v.w;
        sq += v.x * v.x + v.y * v.y + v.z * v.z + v.w * v.w;
    }
    __shared__ float ls[256], lq[256];
    ls[t] = s; lq[t] = sq;
    __syncthreads();
    for (int o = 128; o > 0; o >>= 1) {
        if (t < o) { ls[t] += ls[t + o]; lq[t] += lq[t + o]; }
        __syncthreads();
    }
    if (t == 0) { atomicAdd(&sums[j], ls[0]); atomicAdd(&sumsq[j], lq[0]); }
}

__global__ void k_bnfinal(const float* __restrict__ sums, const float* __restrict__ sumsq,
                          const float* __restrict__ gamma, const float* __restrict__ beta_,
                          float* __restrict__ scale, float* __restrict__ shift) {
    int j = threadIdx.x;                 // 128
    float m    = sums[j] * (1.0f / CNTF);
    float var  = sumsq[j] * (1.0f / CNTF) - m * m;
    float istd = rsqrtf(var + EPS);
    float g    = gamma[j] * istd;
    scale[j] = g;
    shift[j] = beta_[j] - m * g;
}

__global__ void k_apply(float* __restrict__ S, const float* __restrict__ scale,
                        const float* __restrict__ shift) {
    const int total4 = (NB * COUT * NNODE) / 4;   // 12,582,912
    int stride = gridDim.x * blockDim.x;
    for (int idx = blockIdx.x * blockDim.x + threadIdx.x; idx < total4; idx += stride) {
        int rowIdx = idx / (NNODE / 4);
        int j = rowIdx & 127;
        float sc = scale[j], sh = shift[j];
        float4 v = ((const float4*)S)[idx];
        v.x = fmaxf(v.x * sc + sh, 0.f);
        v.y = fmaxf(v.y * sc + sh, 0.f);
        v.z = fmaxf(v.z * sc + sh, 0.f);
        v.w = fmaxf(v.w * sc + sh, 0.f);
        ((float4*)S)[idx] = v;
    }
}

// ---------------- launcher ----------------

extern "C" void kernel_launch(void* const* d_in, const int* in_sizes, int n_in,
                              void* d_out, int out_size, void* d_ws, size_t ws_size,
                              hipStream_t stream) {
    const float* x     = (const float*)d_in[0];
    const int*   ei    = (const int*)  d_in[1];
    const float* ew    = (const float*)d_in[2];
    const float* W     = (const float*)d_in[3];
    const float* bias  = (const float*)d_in[4];
    const float* gamma = (const float*)d_in[5];
    const float* beta_ = (const float*)d_in[6];
    float* S = (float*)d_out;

    char* ws = (char*)d_ws;
    size_t off = 0;
    auto alloc = [&](size_t bytes) -> char* {
        char* p = ws + off;
        off = (off + bytes + 255) & ~(size_t)255;
        return p;
    };
    float* deg   = (float*)alloc(NNODE * 4);
    int*   cnt   = (int*)  alloc(NNODE * 4);
    int*   cur   = (int*)  alloc(NNODE * 4);
    float* sums  = (float*)alloc(128 * 4);
    float* sumsq = (float*)alloc(128 * 4);
    size_t zeroBytes = off;                      // deg,cnt,cur,sums,sumsq need zero
    float* dinv   = (float*)alloc(NNODE * 4);
    int*   rowptr = (int*)  alloc((NNODE + 1) * 4);
    float* scale  = (float*)alloc(128 * 4);
    float* shift  = (float*)alloc(128 * 4);
    int2*  ev     = (int2*) alloc(NEDGE * 8);

    const size_t TB = (size_t)NNODE * ROWF * 4;  // 100,663,296 B per T buffer
    bool pathA = (off + 5 * TB) <= ws_size;      // 508 MB full path, else 206 MB ping-pong
    int nT = pathA ? 5 : 2;
    float* T[5];
    for (int i = 0; i < 5; ++i) T[i] = (float*)(ws + off + (size_t)(i % nT) * TB);

    hipMemsetAsync(ws, 0, zeroBytes, stream);

    k_deg    <<<NEDGE / 256, 256, 0, stream>>>(ei, ew, deg);
    k_dinv   <<<NNODE / 256, 256, 0, stream>>>(deg, dinv);
    k_count  <<<NEDGE / 256, 256, 0, stream>>>(ei, cnt);
    k_scan   <<<1, 1024, 0, stream>>>(cnt, rowptr);
    k_scatter<<<NEDGE / 256, 256, 0, stream>>>(ei, ew, dinv, rowptr, cur, ev);

    k_transpose<<<dim3(NNODE / 32, ROWF / 32), dim3(32, 8), 0, stream>>>(x, T[0]);

    // T1 = L^ T0
    k_prop<<<NNODE / 4, 256, 0, stream>>>(T[0], T[0], T[1], rowptr, ev, 1.f, 0.f);

    if (pathA) {
        k_prop<<<NNODE / 4, 256, 0, stream>>>(T[1], T[0], T[2], rowptr, ev, 2.f, -1.f);
        k_prop<<<NNODE / 4, 256, 0, stream>>>(T[2], T[1], T[3], rowptr, ev, 2.f, -1.f);
        k_prop<<<NNODE / 4, 256, 0, stream>>>(T[3], T[2], T[4], rowptr, ev, 2.f, -1.f);
        k_gemm<<<3072, 256, 0, stream>>>(S, T[0], T[1], T[2], T[3], T[4], W, bias,
                                         sums, sumsq, 0, 5, 1, 1);
    } else {
        k_gemm<<<3072, 256, 0, stream>>>(S, T[0], T[1], nullptr, nullptr, nullptr, W, bias,
                                         sums, sumsq, 0, 2, 1, 0);
        k_prop<<<NNODE / 4, 256, 0, stream>>>(T[1], T[0], T[2], rowptr, ev, 2.f, -1.f); // in-place over T0
        k_gemm<<<3072, 256, 0, stream>>>(S, T[2], nullptr, nullptr, nullptr, nullptr, W, bias,
                                         sums, sumsq, 2, 1, 0, 0);
        k_prop<<<NNODE / 4, 256, 0, stream>>>(T[2], T[1], T[3], rowptr, ev, 2.f, -1.f); // over T1
        k_gemm<<<3072, 256, 0, stream>>>(S, T[3], nullptr, nullptr, nullptr, nullptr, W, bias,
                                         sums, sumsq, 3, 1, 0, 0);
        k_prop<<<NNODE / 4, 256, 0, stream>>>(T[3], T[2], T[4], rowptr, ev, 2.f, -1.f); // over T0
        k_gemm<<<3072, 256, 0, stream>>>(S, T[4], nullptr, nullptr, nullptr, nullptr, W, bias,
                                         sums, sumsq, 4, 1, 0, 0);
        k_bnstats<<<NB * 128, 256, 0, stream>>>(S, sums, sumsq);
    }

    k_bnfinal<<<1, 128, 0, stream>>>(sums, sumsq, gamma, beta_, scale, shift);
    k_apply  <<<3072, 256, 0, stream>>>(S, scale, shift);
}